// Round 2
// baseline (174.945 us; speedup 1.0000x reference)
//
#include <hip/hip_runtime.h>
#include <hip/hip_bf16.h>

// B=32, T=1024, D=256 fixed by the reference problem.
typedef __attribute__((ext_vector_type(8))) short bf16x8;
typedef __attribute__((ext_vector_type(4))) float f32x4;

#define INVT (1.0f/0.07f)

static __device__ __forceinline__ short f2bf(float f){
    unsigned int u = __float_as_uint(f);
    unsigned int r = (u + 0x7fffu + ((u >> 16) & 1u)) >> 16;
    return (short)r;
}
static __device__ __forceinline__ float bf2f(short s){
    return __uint_as_float(((unsigned int)(unsigned short)s) << 16);
}

// async global->LDS, 16B per lane; LDS dest = wave-uniform base + lane*16
static __device__ __forceinline__ void gld16(const void* g, void* l){
    __builtin_amdgcn_global_load_lds(
        (const __attribute__((address_space(1))) unsigned int*)g,
        (__attribute__((address_space(3))) unsigned int*)l, 16, 0, 0);
}

// ---- prep: blocks 0..511 convert W to bf16; blocks 512..543 per-batch rank scan + zero bsum
__global__ __launch_bounds__(256) void prep_kernel(const float* __restrict__ Weeg,
                                                   const float* __restrict__ Weye,
                                                   const int* __restrict__ mask,
                                                   short* __restrict__ Wout,
                                                   int* __restrict__ rank,
                                                   int* __restrict__ idx,
                                                   int* __restrict__ Tv,
                                                   float* __restrict__ bsum){
    __shared__ int ssum[256];
    int tid = threadIdx.x;
    if (blockIdx.x < 512){
        int i = blockIdx.x * 256 + tid;
        float v = (i < 65536) ? Weeg[i] : Weye[i - 65536];
        Wout[i] = f2bf(v);
        return;
    }
    int b = blockIdx.x - 512;
    if (tid == 0) bsum[b] = 0.f;
    int local[4]; int s = 0;
    #pragma unroll
    for (int q = 0; q < 4; ++q){
        int t = tid*4 + q;
        local[q] = (mask[b*1024 + t] > 0) ? 1 : 0;
        s += local[q];
    }
    ssum[tid] = s;
    __syncthreads();
    for (int off = 1; off < 256; off <<= 1){
        int add = (tid >= off) ? ssum[tid - off] : 0;
        __syncthreads();
        ssum[tid] += add;
        __syncthreads();
    }
    int run = ssum[tid] - s;
    #pragma unroll
    for (int q = 0; q < 4; ++q){
        int t = tid*4 + q;
        int g = b*1024 + t;
        run += local[q];
        rank[g] = run - 1;
        if (local[q]) idx[b*1024 + run - 1] = t;
    }
    if (tid == 255) Tv[b] = ssum[255];
}

// ---- fused projection + L2 normalize, both modalities (blockIdx.y selects).
__global__ __launch_bounds__(256, 2) void proj_kernel(const float* __restrict__ Aeeg,
                                                      const float* __restrict__ Aeye,
                                                      const short* __restrict__ Wbf,
                                                      short* __restrict__ Eout,
                                                      short* __restrict__ Vout){
    __shared__ short sW[2][64 * 256];   // 2 x 32KB, XOR-swizzled in 16B blocks
    int sel = blockIdx.y;
    const float* A   = sel ? Aeye : Aeeg;
    const short* W   = Wbf + sel * 65536;
    short*       Out = sel ? Vout : Eout;

    int tid = threadIdx.x;
    int w = tid >> 6, lane = tid & 63;
    int l15 = lane & 15, lq = lane >> 4;
    int kb  = lq * 8;
    int row0 = blockIdx.x * 64;

    int ro   = lane >> 5;
    int cs   = lane & 31;
    int s7   = l15 & 7;

    #pragma unroll
    for (int p = 0; p < 8; ++p){
        int rr = (p*2 + ro) & 7;
        gld16(W + (size_t)(w*16 + p*2 + ro)*256 + (cs ^ rr)*8,
              &sW[0][(w*16 + p*2) * 256]);
    }
    #pragma unroll
    for (int p = 0; p < 8; ++p){
        int rr = (p*2 + ro) & 7;
        gld16(W + (size_t)(64 + w*16 + p*2 + ro)*256 + (cs ^ rr)*8,
              &sW[1][(w*16 + p*2) * 256]);
    }

    bf16x8 xf[8];
    {
        const float* ap = A + (size_t)(row0 + w*16 + l15) * 256 + kb;
        #pragma unroll
        for (int g = 0; g < 8; ++g){
            float4 x0 = *(const float4*)(ap + g*32);
            float4 x1 = *(const float4*)(ap + g*32 + 4);
            bf16x8 t;
            t[0]=f2bf(x0.x); t[1]=f2bf(x0.y); t[2]=f2bf(x0.z); t[3]=f2bf(x0.w);
            t[4]=f2bf(x1.x); t[5]=f2bf(x1.y); t[6]=f2bf(x1.z); t[7]=f2bf(x1.w);
            xf[g] = t;
        }
    }

    f32x4 acc[16];
    #pragma unroll
    for (int q = 0; q < 16; ++q) acc[q] = (f32x4){0.f,0.f,0.f,0.f};

    __syncthreads();

    #pragma unroll
    for (int nt = 0; nt < 4; ++nt){
        f32x4 c = acc[nt];
        int rbase = (nt*16 + l15) * 256;
        #pragma unroll
        for (int g = 0; g < 8; ++g){
            bf16x8 wf = *(const bf16x8*)&sW[0][rbase + (((g*4 + lq) ^ s7) << 3)];
            c = __builtin_amdgcn_mfma_f32_16x16x32_bf16(wf, xf[g], c, 0, 0, 0);
        }
        acc[nt] = c;
    }

    __syncthreads();

    #pragma unroll
    for (int p = 0; p < 8; ++p){
        int rr = (p*2 + ro) & 7;
        gld16(W + (size_t)(128 + w*16 + p*2 + ro)*256 + (cs ^ rr)*8,
              &sW[0][(w*16 + p*2) * 256]);
    }
    #pragma unroll
    for (int nt = 0; nt < 4; ++nt){
        f32x4 c = acc[4 + nt];
        int rbase = (nt*16 + l15) * 256;
        #pragma unroll
        for (int g = 0; g < 8; ++g){
            bf16x8 wf = *(const bf16x8*)&sW[1][rbase + (((g*4 + lq) ^ s7) << 3)];
            c = __builtin_amdgcn_mfma_f32_16x16x32_bf16(wf, xf[g], c, 0, 0, 0);
        }
        acc[4 + nt] = c;
    }

    __syncthreads();

    #pragma unroll
    for (int p = 0; p < 8; ++p){
        int rr = (p*2 + ro) & 7;
        gld16(W + (size_t)(192 + w*16 + p*2 + ro)*256 + (cs ^ rr)*8,
              &sW[1][(w*16 + p*2) * 256]);
    }
    #pragma unroll
    for (int nt = 0; nt < 4; ++nt){
        f32x4 c = acc[8 + nt];
        int rbase = (nt*16 + l15) * 256;
        #pragma unroll
        for (int g = 0; g < 8; ++g){
            bf16x8 wf = *(const bf16x8*)&sW[0][rbase + (((g*4 + lq) ^ s7) << 3)];
            c = __builtin_amdgcn_mfma_f32_16x16x32_bf16(wf, xf[g], c, 0, 0, 0);
        }
        acc[8 + nt] = c;
    }

    __syncthreads();

    #pragma unroll
    for (int nt = 0; nt < 4; ++nt){
        f32x4 c = acc[12 + nt];
        int rbase = (nt*16 + l15) * 256;
        #pragma unroll
        for (int g = 0; g < 8; ++g){
            bf16x8 wf = *(const bf16x8*)&sW[1][rbase + (((g*4 + lq) ^ s7) << 3)];
            c = __builtin_amdgcn_mfma_f32_16x16x32_bf16(wf, xf[g], c, 0, 0, 0);
        }
        acc[12 + nt] = c;
    }

    float ss = 0.f;
    #pragma unroll
    for (int q = 0; q < 16; ++q){
        #pragma unroll
        for (int r = 0; r < 4; ++r){ float x = acc[q][r]; ss += x*x; }
    }
    ss += __shfl_xor(ss, 16);
    ss += __shfl_xor(ss, 32);
    float scale = 1.0f / fmaxf(sqrtf(ss), 1e-12f);

    short* twrow = &sW[0][(w*16 + l15) * 256];
    #pragma unroll
    for (int q = 0; q < 16; ++q){
        short4 pk;
        pk.x = f2bf(acc[q][0] * scale);
        pk.y = f2bf(acc[q][1] * scale);
        pk.z = f2bf(acc[q][2] * scale);
        pk.w = f2bf(acc[q][3] * scale);
        int c    = (q >> 2) * 64 + (q & 3) * 16 + lq*4;
        int blk  = (c >> 3) ^ s7;
        *(short4*)(twrow + blk*8 + (c & 7)) = pk;
    }
    short* op = Out + (size_t)(row0 + w*16) * 256;
    #pragma unroll
    for (int p = 0; p < 8; ++p){
        int rloc = p*2 + (lane >> 5);
        int gblk = lane & 31;
        const short* tr = &sW[0][(w*16 + rloc) * 256 + ((gblk ^ (rloc & 7)) * 8)];
        *(int4*)(op + rloc*256 + gblk*8) = *(const int4*)tr;
    }
}

// ---- loss: rank-compacted barrier-free flash-LSE. Only the ~Tv x Tv valid
// sub-matrix is computed (Tv ~ 512 -> ~4x less MFMA than dense). One wave per
// block; wave owns 32 compact i-rows x one 256-col compact j-quarter of batch
// b. E/V rows gathered through idx; ragged tail masked in-register from Tv.
// No LDS, no barriers. Inactive j-quarters zero-fill their psum slice so the
// 4-slice sum in reduce stays exact. XCD-pinned: b&7 == blockIdx&7.
__global__ __launch_bounds__(64) void loss_kernel(const short* __restrict__ E,
                                                  const short* __restrict__ V,
                                                  const int* __restrict__ idx,
                                                  const int* __restrict__ Tv,
                                                  float* __restrict__ psum){
    int n  = blockIdx.x;                        // 0..4095
    int b  = (((n >> 3) & 3) << 3) | (n & 7);   // 0..31, XCD-pinned to n&7
    int it = (n >> 5) & 31;                     // i-tile: 32 compact rows
    int js = n >> 10;                           // j-quarter: 256 compact cols

    int tv = Tv[b];
    int lane = threadIdx.x;
    int l15 = lane & 15, lq = lane >> 4;

    if (it*32 >= tv) return;                    // rows never read downstream

    if (js*256 >= tv){                          // empty quarter: publish zeros
        if (lane < 32) psum[(size_t)js*32768 + b*1024 + it*32 + lane] = 0.f;
        return;
    }

    const int* ib = idx + b*1024;

    // gathered A-fragments: 32 compact i-rows x K=256, register-resident
    int rA0 = it*32 + l15;
    int rA1 = rA0 + 16;
    int iA0 = (rA0 < tv) ? ib[rA0] : ib[0];
    int iA1 = (rA1 < tv) ? ib[rA1] : ib[0];
    bf16x8 af0[8], af1[8];
    {
        const short* e0 = E + ((size_t)b*1024 + iA0)*256 + lq*8;
        const short* e1 = E + ((size_t)b*1024 + iA1)*256 + lq*8;
        #pragma unroll
        for (int g = 0; g < 8; ++g){
            af0[g] = *(const bf16x8*)(e0 + g*32);
            af1[g] = *(const bf16x8*)(e1 + g*32);
        }
    }

    // per-tile gathered column index + ragged-tail mask (in-register, no cb)
    int   iv[16];
    float ce[16];
    #pragma unroll
    for (int jt = 0; jt < 16; ++jt){
        int r  = js*256 + jt*16 + l15;
        int ok = r < tv;
        iv[jt] = ok ? ib[r] : ib[0];
        ce[jt] = ok ? 0.0f : -1e9f;
    }

    const short* vb = V + (size_t)b*1024*256 + lq*8;

    float ls0[4] = {0.f,0.f,0.f,0.f};
    float ls1[4] = {0.f,0.f,0.f,0.f};

    bf16x8 ba[8], bb[8];
    {   // prologue: tile 0
        const short* vp = vb + (size_t)iv[0]*256;
        #pragma unroll
        for (int g = 0; g < 8; ++g) ba[g] = *(const bf16x8*)(vp + g*32);
    }

    #pragma unroll
    for (int p = 0; p < 8; ++p){
        // prefetch tile 2p+1 into bb (overlaps ba's MFMAs)
        {
            const short* vp = vb + (size_t)iv[2*p+1]*256;
            #pragma unroll
            for (int g = 0; g < 8; ++g) bb[g] = *(const bf16x8*)(vp + g*32);
        }
        // compute tile 2p from ba
        {
            f32x4 a0 = (f32x4){0.f,0.f,0.f,0.f};
            f32x4 a1 = (f32x4){0.f,0.f,0.f,0.f};
            #pragma unroll
            for (int g = 0; g < 8; ++g){
                a0 = __builtin_amdgcn_mfma_f32_16x16x32_bf16(af0[g], ba[g], a0, 0, 0, 0);
                a1 = __builtin_amdgcn_mfma_f32_16x16x32_bf16(af1[g], ba[g], a1, 0, 0, 0);
            }
            float m = ce[2*p];
            #pragma unroll
            for (int r = 0; r < 4; ++r){
                ls0[r] += __expf(fmaf(a0[r], INVT, m));
                ls1[r] += __expf(fmaf(a1[r], INVT, m));
            }
        }
        // prefetch tile 2p+2 into ba (overlaps bb's MFMAs)
        if (p < 7){
            const short* vp = vb + (size_t)iv[2*p+2]*256;
            #pragma unroll
            for (int g = 0; g < 8; ++g) ba[g] = *(const bf16x8*)(vp + g*32);
        }
        // compute tile 2p+1 from bb
        {
            f32x4 a0 = (f32x4){0.f,0.f,0.f,0.f};
            f32x4 a1 = (f32x4){0.f,0.f,0.f,0.f};
            #pragma unroll
            for (int g = 0; g < 8; ++g){
                a0 = __builtin_amdgcn_mfma_f32_16x16x32_bf16(af0[g], bb[g], a0, 0, 0, 0);
                a1 = __builtin_amdgcn_mfma_f32_16x16x32_bf16(af1[g], bb[g], a1, 0, 0, 0);
            }
            float m = ce[2*p+1];
            #pragma unroll
            for (int r = 0; r < 4; ++r){
                ls0[r] += __expf(fmaf(a0[r], INVT, m));
                ls1[r] += __expf(fmaf(a1[r], INVT, m));
            }
        }
    }

    // reduce over the 16 lanes sharing each i-row (l15 = j within tile)
    #pragma unroll
    for (int r = 0; r < 4; ++r){
        float v0 = ls0[r], v1 = ls1[r];
        #pragma unroll
        for (int mm = 1; mm < 16; mm <<= 1){
            v0 += __shfl_xor(v0, mm);
            v1 += __shfl_xor(v1, mm);
        }
        ls0[r] = v0; ls1[r] = v1;
    }

    if (l15 == 0){  // lanes 0,16,32,48; row-within-tile = lq*4 + r (+16 for s=1)
        float* pp = psum + (size_t)js*32768 + b*1024 + it*32;
        #pragma unroll
        for (int r = 0; r < 4; ++r){
            pp[lq*4 + r]      = ls0[r];
            pp[16 + lq*4 + r] = ls1[r];
        }
    }
}

// ---- banded positive max: one 16-lane group per row, <=5 candidate cols via idx.
__global__ __launch_bounds__(256) void pos_kernel(const short* __restrict__ E,
                                                  const short* __restrict__ V,
                                                  const int* __restrict__ mask,
                                                  const int* __restrict__ rank,
                                                  const int* __restrict__ idx,
                                                  const int* __restrict__ Tv,
                                                  float* __restrict__ pmax){
    int tid = threadIdx.x;
    int gl  = tid & 15;
    int rf  = (blockIdx.x * 256 + tid) >> 4;   // 0..32767
    int b   = rf >> 10;
    if (mask[rf] <= 0) return;

    int ri = rank[rf];
    int tv = Tv[b];
    int lo = ri - 2; if (lo < 0) lo = 0;
    int hi = ri + 2; if (hi > tv - 1) hi = tv - 1;

    const short* epp = E + (size_t)rf * 256 + gl * 16;
    float ev[16];
    {
        bf16x8 e0 = *(const bf16x8*)epp;
        bf16x8 e1 = *(const bf16x8*)(epp + 8);
        #pragma unroll
        for (int k = 0; k < 8; ++k){ ev[k] = bf2f(e0[k]); ev[8+k] = bf2f(e1[k]); }
    }
    float pm = -1e30f;
    for (int r = lo; r <= hi; ++r){
        int j = idx[b*1024 + r];
        const short* vpp = V + ((size_t)(b*1024) + j) * 256 + gl * 16;
        bf16x8 v0 = *(const bf16x8*)vpp;
        bf16x8 v1 = *(const bf16x8*)(vpp + 8);
        float s = 0.f;
        #pragma unroll
        for (int k = 0; k < 8; ++k){
            s = fmaf(ev[k],   bf2f(v0[k]), s);
            s = fmaf(ev[8+k], bf2f(v1[k]), s);
        }
        s += __shfl_xor(s, 1);
        s += __shfl_xor(s, 2);
        s += __shfl_xor(s, 4);
        s += __shfl_xor(s, 8);
        pm = fmaxf(pm, s);
    }
    if (gl == 0) pmax[rf] = pm * INVT;
}

// ---- partial reduce: psum is rank-indexed with 4 j-quarter slices.
__global__ __launch_bounds__(256) void reduce_kernel(const float* __restrict__ psum,
                                                     const float* __restrict__ pmax,
                                                     const int* __restrict__ mask,
                                                     const int* __restrict__ rank,
                                                     float* __restrict__ bsum){
    int b  = blockIdx.x >> 2;
    int i  = (blockIdx.x & 3) * 256 + threadIdx.x;
    int g  = b*1024 + i;
    float a = 0.f;
    if (mask[g] > 0){
        const float* pp = psum + b*1024 + rank[g];
        float ps = pp[0] + pp[32768] + pp[65536] + pp[98304];
        a = logf(ps) - pmax[g];
    }
    #pragma unroll
    for (int m = 1; m < 64; m <<= 1) a += __shfl_xor(a, m);
    if ((threadIdx.x & 63) == 0 && a != 0.f) atomicAdd(&bsum[b], a);
}

// ---- final: out = sum_b (Tv>=2 ? bsum/Tv : 0) / 32
__global__ void final_kernel(const float* __restrict__ bsum,
                             const int* __restrict__ Tv,
                             float* __restrict__ out){
    int tid = threadIdx.x;
    float v = 0.f;
    if (tid < 32){
        int tv = Tv[tid];
        if (tv >= 2) v = bsum[tid] / (float)tv;
    }
    #pragma unroll
    for (int m = 1; m < 64; m <<= 1) v += __shfl_xor(v, m);
    if (tid == 0) out[0] = v / 32.0f;
}

extern "C" void kernel_launch(void* const* d_in, const int* in_sizes, int n_in,
                              void* d_out, int out_size, void* d_ws, size_t ws_size,
                              hipStream_t stream) {
    const float* eeg  = (const float*)d_in[0];
    const float* eye  = (const float*)d_in[1];
    const int*   mask = (const int*)d_in[2];
    const float* Weeg = (const float*)d_in[3];
    const float* Weye = (const float*)d_in[4];
    float* out = (float*)d_out;

    char* ws = (char*)d_ws;
    short* e_bf  = (short*)(ws);                       // 16 MiB
    short* v_bf  = (short*)(ws + 16777216);            // 16 MiB
    short* wbf   = (short*)(ws + 33554432);            // 256 KiB
    int*   rank  = (int*)  (ws + 33816576);            // 128 KiB
    int*   idx   = (int*)  (ws + 33947648);            // 128 KiB
    float* psum  = (float*)(ws + 34209792);            // 512 KiB (4 j-quarters x 32 b x 1024 ranks)
    float* pmax  = (float*)(ws + 34734080);            // 128 KiB
    int*   Tv    = (int*)  (ws + 34865152);            // 128 B
    float* bsum  = (float*)(ws + 34865280);            // 128 B

    prep_kernel<<<544, 256, 0, stream>>>(Weeg, Weye, mask, wbf, rank, idx, Tv, bsum);
    proj_kernel<<<dim3(512, 2), 256, 0, stream>>>(eeg, eye, wbf, e_bf, v_bf);
    loss_kernel<<<4096, 64, 0, stream>>>(e_bf, v_bf, idx, Tv, psum);
    pos_kernel<<<2048, 256, 0, stream>>>(e_bf, v_bf, mask, rank, idx, Tv, pmax);
    reduce_kernel<<<128, 256, 0, stream>>>(psum, pmax, mask, rank, bsum);
    final_kernel<<<1, 64, 0, stream>>>(bsum, Tv, out);
}

// Round 3
// 172.602 us; speedup vs baseline: 1.0136x; 1.0136x over previous
//
#include <hip/hip_runtime.h>
#include <hip/hip_bf16.h>

// B=32, T=1024, D=256 fixed by the reference problem.
typedef __attribute__((ext_vector_type(8))) short bf16x8;
typedef __attribute__((ext_vector_type(4))) float f32x4;

#define INVT (1.0f/0.07f)

static __device__ __forceinline__ short f2bf(float f){
    unsigned int u = __float_as_uint(f);
    unsigned int r = (u + 0x7fffu + ((u >> 16) & 1u)) >> 16;
    return (short)r;
}
static __device__ __forceinline__ float bf2f(short s){
    return __uint_as_float(((unsigned int)(unsigned short)s) << 16);
}

// async global->LDS, 16B per lane; LDS dest = wave-uniform base + lane*16
static __device__ __forceinline__ void gld16(const void* g, void* l){
    __builtin_amdgcn_global_load_lds(
        (const __attribute__((address_space(1))) unsigned int*)g,
        (__attribute__((address_space(3))) unsigned int*)l, 16, 0, 0);
}

// ---- prep: blocks 0..511 convert W to bf16; blocks 512..543 per-batch rank scan + zero bsum
__global__ __launch_bounds__(256) void prep_kernel(const float* __restrict__ Weeg,
                                                   const float* __restrict__ Weye,
                                                   const int* __restrict__ mask,
                                                   short* __restrict__ Wout,
                                                   int* __restrict__ rank,
                                                   int* __restrict__ idx,
                                                   int* __restrict__ Tv,
                                                   float* __restrict__ cb,
                                                   float* __restrict__ bsum){
    __shared__ int ssum[256];
    int tid = threadIdx.x;
    if (blockIdx.x < 512){
        int i = blockIdx.x * 256 + tid;
        float v = (i < 65536) ? Weeg[i] : Weye[i - 65536];
        Wout[i] = f2bf(v);
        return;
    }
    int b = blockIdx.x - 512;
    if (tid == 0) bsum[b] = 0.f;
    int local[4]; int s = 0;
    #pragma unroll
    for (int q = 0; q < 4; ++q){
        int t = tid*4 + q;
        local[q] = (mask[b*1024 + t] > 0) ? 1 : 0;
        s += local[q];
    }
    ssum[tid] = s;
    __syncthreads();
    for (int off = 1; off < 256; off <<= 1){
        int add = (tid >= off) ? ssum[tid - off] : 0;
        __syncthreads();
        ssum[tid] += add;
        __syncthreads();
    }
    int run = ssum[tid] - s;
    #pragma unroll
    for (int q = 0; q < 4; ++q){
        int t = tid*4 + q;
        int g = b*1024 + t;
        run += local[q];
        rank[g] = run - 1;
        cb[g]   = local[q] ? 0.0f : -1e9f;
        if (local[q]) idx[b*1024 + run - 1] = t;
    }
    if (tid == 255) Tv[b] = ssum[255];
}

// ---- fused projection + L2 normalize, both modalities (blockIdx.y selects).
__global__ __launch_bounds__(256, 2) void proj_kernel(const float* __restrict__ Aeeg,
                                                      const float* __restrict__ Aeye,
                                                      const short* __restrict__ Wbf,
                                                      short* __restrict__ Eout,
                                                      short* __restrict__ Vout){
    __shared__ short sW[2][64 * 256];   // 2 x 32KB, XOR-swizzled in 16B blocks
    int sel = blockIdx.y;
    const float* A   = sel ? Aeye : Aeeg;
    const short* W   = Wbf + sel * 65536;
    short*       Out = sel ? Vout : Eout;

    int tid = threadIdx.x;
    int w = tid >> 6, lane = tid & 63;
    int l15 = lane & 15, lq = lane >> 4;
    int kb  = lq * 8;
    int row0 = blockIdx.x * 64;

    int ro   = lane >> 5;
    int cs   = lane & 31;
    int s7   = l15 & 7;

    #pragma unroll
    for (int p = 0; p < 8; ++p){
        int rr = (p*2 + ro) & 7;
        gld16(W + (size_t)(w*16 + p*2 + ro)*256 + (cs ^ rr)*8,
              &sW[0][(w*16 + p*2) * 256]);
    }
    #pragma unroll
    for (int p = 0; p < 8; ++p){
        int rr = (p*2 + ro) & 7;
        gld16(W + (size_t)(64 + w*16 + p*2 + ro)*256 + (cs ^ rr)*8,
              &sW[1][(w*16 + p*2) * 256]);
    }

    bf16x8 xf[8];
    {
        const float* ap = A + (size_t)(row0 + w*16 + l15) * 256 + kb;
        #pragma unroll
        for (int g = 0; g < 8; ++g){
            float4 x0 = *(const float4*)(ap + g*32);
            float4 x1 = *(const float4*)(ap + g*32 + 4);
            bf16x8 t;
            t[0]=f2bf(x0.x); t[1]=f2bf(x0.y); t[2]=f2bf(x0.z); t[3]=f2bf(x0.w);
            t[4]=f2bf(x1.x); t[5]=f2bf(x1.y); t[6]=f2bf(x1.z); t[7]=f2bf(x1.w);
            xf[g] = t;
        }
    }

    f32x4 acc[16];
    #pragma unroll
    for (int q = 0; q < 16; ++q) acc[q] = (f32x4){0.f,0.f,0.f,0.f};

    __syncthreads();

    #pragma unroll
    for (int nt = 0; nt < 4; ++nt){
        f32x4 c = acc[nt];
        int rbase = (nt*16 + l15) * 256;
        #pragma unroll
        for (int g = 0; g < 8; ++g){
            bf16x8 wf = *(const bf16x8*)&sW[0][rbase + (((g*4 + lq) ^ s7) << 3)];
            c = __builtin_amdgcn_mfma_f32_16x16x32_bf16(wf, xf[g], c, 0, 0, 0);
        }
        acc[nt] = c;
    }

    __syncthreads();

    #pragma unroll
    for (int p = 0; p < 8; ++p){
        int rr = (p*2 + ro) & 7;
        gld16(W + (size_t)(128 + w*16 + p*2 + ro)*256 + (cs ^ rr)*8,
              &sW[0][(w*16 + p*2) * 256]);
    }
    #pragma unroll
    for (int nt = 0; nt < 4; ++nt){
        f32x4 c = acc[4 + nt];
        int rbase = (nt*16 + l15) * 256;
        #pragma unroll
        for (int g = 0; g < 8; ++g){
            bf16x8 wf = *(const bf16x8*)&sW[1][rbase + (((g*4 + lq) ^ s7) << 3)];
            c = __builtin_amdgcn_mfma_f32_16x16x32_bf16(wf, xf[g], c, 0, 0, 0);
        }
        acc[4 + nt] = c;
    }

    __syncthreads();

    #pragma unroll
    for (int p = 0; p < 8; ++p){
        int rr = (p*2 + ro) & 7;
        gld16(W + (size_t)(192 + w*16 + p*2 + ro)*256 + (cs ^ rr)*8,
              &sW[1][(w*16 + p*2) * 256]);
    }
    #pragma unroll
    for (int nt = 0; nt < 4; ++nt){
        f32x4 c = acc[8 + nt];
        int rbase = (nt*16 + l15) * 256;
        #pragma unroll
        for (int g = 0; g < 8; ++g){
            bf16x8 wf = *(const bf16x8*)&sW[0][rbase + (((g*4 + lq) ^ s7) << 3)];
            c = __builtin_amdgcn_mfma_f32_16x16x32_bf16(wf, xf[g], c, 0, 0, 0);
        }
        acc[8 + nt] = c;
    }

    __syncthreads();

    #pragma unroll
    for (int nt = 0; nt < 4; ++nt){
        f32x4 c = acc[12 + nt];
        int rbase = (nt*16 + l15) * 256;
        #pragma unroll
        for (int g = 0; g < 8; ++g){
            bf16x8 wf = *(const bf16x8*)&sW[1][rbase + (((g*4 + lq) ^ s7) << 3)];
            c = __builtin_amdgcn_mfma_f32_16x16x32_bf16(wf, xf[g], c, 0, 0, 0);
        }
        acc[12 + nt] = c;
    }

    float ss = 0.f;
    #pragma unroll
    for (int q = 0; q < 16; ++q){
        #pragma unroll
        for (int r = 0; r < 4; ++r){ float x = acc[q][r]; ss += x*x; }
    }
    ss += __shfl_xor(ss, 16);
    ss += __shfl_xor(ss, 32);
    float scale = 1.0f / fmaxf(sqrtf(ss), 1e-12f);

    short* twrow = &sW[0][(w*16 + l15) * 256];
    #pragma unroll
    for (int q = 0; q < 16; ++q){
        short4 pk;
        pk.x = f2bf(acc[q][0] * scale);
        pk.y = f2bf(acc[q][1] * scale);
        pk.z = f2bf(acc[q][2] * scale);
        pk.w = f2bf(acc[q][3] * scale);
        int c    = (q >> 2) * 64 + (q & 3) * 16 + lq*4;
        int blk  = (c >> 3) ^ s7;
        *(short4*)(twrow + blk*8 + (c & 7)) = pk;
    }
    short* op = Out + (size_t)(row0 + w*16) * 256;
    #pragma unroll
    for (int p = 0; p < 8; ++p){
        int rloc = p*2 + (lane >> 5);
        int gblk = lane & 31;
        const short* tr = &sW[0][(w*16 + rloc) * 256 + ((gblk ^ (rloc & 7)) * 8)];
        *(int4*)(op + rloc*256 + gblk*8) = *(const int4*)tr;
    }
}

// ---- loss: dense barrier-free flash-LSE, j-QUARTER split for 2x TLP.
// One wave per block; wave owns 64 i-rows (A-frags register-resident) and
// streams 256 contiguous j-rows of V as MFMA B-frags. No LDS, no barriers,
// no gather on the stream side (invalid cols masked via cb = -1e9).
// 2048 waves = 8/CU resident (2/SIMD at ~240 VGPR). XCD-pinned: b&7 == n&7.
// psum has 4 j-quarter slices.
__global__ __launch_bounds__(64) void loss_kernel(const short* __restrict__ E,
                                                  const short* __restrict__ V,
                                                  const float* __restrict__ cb,
                                                  float* __restrict__ psum){
    int n  = blockIdx.x;                        // 0..2047
    int b  = (((n >> 3) & 3) << 3) | (n & 7);   // 0..31, XCD-pinned to n&7
    int r2 = n >> 5;                            // 0..63
    int it = r2 & 15;                           // i-tile of 64 rows
    int jq = r2 >> 4;                           // j-quarter (0..3)

    int lane = threadIdx.x;
    int l15 = lane & 15, lq = lane >> 4;

    // A-fragments: 64 i-rows x K=256, register-resident, loaded once.
    bf16x8 af[4][8];
    {
        const short* ep = E + ((size_t)b*1024 + it*64 + l15) * 256 + lq*8;
        #pragma unroll
        for (int s = 0; s < 4; ++s)
            #pragma unroll
            for (int g = 0; g < 8; ++g)
                af[s][g] = *(const bf16x8*)(ep + s*16*256 + g*32);
    }

    const short* vp  = V  + ((size_t)b*1024 + jq*256 + l15) * 256 + lq*8;
    const float* cbp = cb + b*1024 + jq*256 + l15;

    float ls[4][4];
    #pragma unroll
    for (int s = 0; s < 4; ++s)
        #pragma unroll
        for (int r = 0; r < 4; ++r) ls[s][r] = 0.f;

    // prologue: tile 0 into ba
    bf16x8 ba[8], bb[8];
    #pragma unroll
    for (int g = 0; g < 8; ++g) ba[g] = *(const bf16x8*)(vp + g*32);
    float ca = cbp[0];
    float cbv;

    #pragma unroll 1
    for (int t = 0; t < 8; ++t){
        // prefetch tile 2t+1 into bb (overlaps ba's MFMAs)
        {
            const short* v1 = vp + (size_t)(2*t + 1) * 16 * 256;
            #pragma unroll
            for (int g = 0; g < 8; ++g) bb[g] = *(const bf16x8*)(v1 + g*32);
            cbv = cbp[(2*t + 1) * 16];
        }
        // compute tile 2t from ba
        {
            f32x4 a0 = (f32x4){0.f,0.f,0.f,0.f};
            f32x4 a1 = (f32x4){0.f,0.f,0.f,0.f};
            f32x4 a2 = (f32x4){0.f,0.f,0.f,0.f};
            f32x4 a3 = (f32x4){0.f,0.f,0.f,0.f};
            #pragma unroll
            for (int g = 0; g < 8; ++g){
                a0 = __builtin_amdgcn_mfma_f32_16x16x32_bf16(af[0][g], ba[g], a0, 0, 0, 0);
                a1 = __builtin_amdgcn_mfma_f32_16x16x32_bf16(af[1][g], ba[g], a1, 0, 0, 0);
                a2 = __builtin_amdgcn_mfma_f32_16x16x32_bf16(af[2][g], ba[g], a2, 0, 0, 0);
                a3 = __builtin_amdgcn_mfma_f32_16x16x32_bf16(af[3][g], ba[g], a3, 0, 0, 0);
            }
            #pragma unroll
            for (int r = 0; r < 4; ++r){
                ls[0][r] += __expf(fmaf(a0[r], INVT, ca));
                ls[1][r] += __expf(fmaf(a1[r], INVT, ca));
                ls[2][r] += __expf(fmaf(a2[r], INVT, ca));
                ls[3][r] += __expf(fmaf(a3[r], INVT, ca));
            }
        }
        // prefetch tile 2t+2 into ba (overlaps bb's MFMAs); skip past end
        if (t < 7){
            const short* v2 = vp + (size_t)(2*t + 2) * 16 * 256;
            #pragma unroll
            for (int g = 0; g < 8; ++g) ba[g] = *(const bf16x8*)(v2 + g*32);
            ca = cbp[(2*t + 2) * 16];
        }
        // compute tile 2t+1 from bb
        {
            f32x4 a0 = (f32x4){0.f,0.f,0.f,0.f};
            f32x4 a1 = (f32x4){0.f,0.f,0.f,0.f};
            f32x4 a2 = (f32x4){0.f,0.f,0.f,0.f};
            f32x4 a3 = (f32x4){0.f,0.f,0.f,0.f};
            #pragma unroll
            for (int g = 0; g < 8; ++g){
                a0 = __builtin_amdgcn_mfma_f32_16x16x32_bf16(af[0][g], bb[g], a0, 0, 0, 0);
                a1 = __builtin_amdgcn_mfma_f32_16x16x32_bf16(af[1][g], bb[g], a1, 0, 0, 0);
                a2 = __builtin_amdgcn_mfma_f32_16x16x32_bf16(af[2][g], bb[g], a2, 0, 0, 0);
                a3 = __builtin_amdgcn_mfma_f32_16x16x32_bf16(af[3][g], bb[g], a3, 0, 0, 0);
            }
            #pragma unroll
            for (int r = 0; r < 4; ++r){
                ls[0][r] += __expf(fmaf(a0[r], INVT, cbv));
                ls[1][r] += __expf(fmaf(a1[r], INVT, cbv));
                ls[2][r] += __expf(fmaf(a2[r], INVT, cbv));
                ls[3][r] += __expf(fmaf(a3[r], INVT, cbv));
            }
        }
    }

    // reduce over the 16 lanes sharing each i-row (l15 = j within tile)
    #pragma unroll
    for (int s = 0; s < 4; ++s)
        #pragma unroll
        for (int r = 0; r < 4; ++r){
            float v = ls[s][r];
            #pragma unroll
            for (int mm = 1; mm < 16; mm <<= 1)
                v += __shfl_xor(v, mm);
            ls[s][r] = v;
        }

    if (l15 == 0){  // lanes 0,16,32,48; lq = lane>>4
        float* pp = psum + (size_t)jq*32768 + (size_t)b*1024 + it*64;
        #pragma unroll
        for (int s = 0; s < 4; ++s)
            #pragma unroll
            for (int r = 0; r < 4; ++r)
                pp[s*16 + lq*4 + r] = ls[s][r];
    }
}

// ---- banded positive max: one 16-lane group per row, <=5 candidate cols via idx.
__global__ __launch_bounds__(256) void pos_kernel(const short* __restrict__ E,
                                                  const short* __restrict__ V,
                                                  const int* __restrict__ mask,
                                                  const int* __restrict__ rank,
                                                  const int* __restrict__ idx,
                                                  const int* __restrict__ Tv,
                                                  float* __restrict__ pmax){
    int tid = threadIdx.x;
    int gl  = tid & 15;
    int rf  = (blockIdx.x * 256 + tid) >> 4;   // 0..32767
    int b   = rf >> 10;
    if (mask[rf] <= 0) return;

    int ri = rank[rf];
    int tv = Tv[b];
    int lo = ri - 2; if (lo < 0) lo = 0;
    int hi = ri + 2; if (hi > tv - 1) hi = tv - 1;

    const short* epp = E + (size_t)rf * 256 + gl * 16;
    float ev[16];
    {
        bf16x8 e0 = *(const bf16x8*)epp;
        bf16x8 e1 = *(const bf16x8*)(epp + 8);
        #pragma unroll
        for (int k = 0; k < 8; ++k){ ev[k] = bf2f(e0[k]); ev[8+k] = bf2f(e1[k]); }
    }
    float pm = -1e30f;
    for (int r = lo; r <= hi; ++r){
        int j = idx[b*1024 + r];
        const short* vpp = V + ((size_t)(b*1024) + j) * 256 + gl * 16;
        bf16x8 v0 = *(const bf16x8*)vpp;
        bf16x8 v1 = *(const bf16x8*)(vpp + 8);
        float s = 0.f;
        #pragma unroll
        for (int k = 0; k < 8; ++k){
            s = fmaf(ev[k],   bf2f(v0[k]), s);
            s = fmaf(ev[8+k], bf2f(v1[k]), s);
        }
        s += __shfl_xor(s, 1);
        s += __shfl_xor(s, 2);
        s += __shfl_xor(s, 4);
        s += __shfl_xor(s, 8);
        pm = fmaxf(pm, s);
    }
    if (gl == 0) pmax[rf] = pm * INVT;
}

// ---- partial reduce: 4 blocks per b, each thread one i; psum has 4 j-quarter slices.
__global__ __launch_bounds__(256) void reduce_kernel(const float* __restrict__ psum,
                                                     const float* __restrict__ pmax,
                                                     const int* __restrict__ mask,
                                                     float* __restrict__ bsum){
    int b  = blockIdx.x >> 2;
    int i  = (blockIdx.x & 3) * 256 + threadIdx.x;
    int g  = b*1024 + i;
    float a = 0.f;
    if (mask[g] > 0){
        float ps = psum[g] + psum[g + 32768] + psum[g + 65536] + psum[g + 98304];
        a = logf(ps) - pmax[g];
    }
    #pragma unroll
    for (int m = 1; m < 64; m <<= 1) a += __shfl_xor(a, m);
    if ((threadIdx.x & 63) == 0 && a != 0.f) atomicAdd(&bsum[b], a);
}

// ---- final: out = sum_b (Tv>=2 ? bsum/Tv : 0) / 32
__global__ void final_kernel(const float* __restrict__ bsum,
                             const int* __restrict__ Tv,
                             float* __restrict__ out){
    int tid = threadIdx.x;
    float v = 0.f;
    if (tid < 32){
        int tv = Tv[tid];
        if (tv >= 2) v = bsum[tid] / (float)tv;
    }
    #pragma unroll
    for (int m = 1; m < 64; m <<= 1) v += __shfl_xor(v, m);
    if (tid == 0) out[0] = v / 32.0f;
}

extern "C" void kernel_launch(void* const* d_in, const int* in_sizes, int n_in,
                              void* d_out, int out_size, void* d_ws, size_t ws_size,
                              hipStream_t stream) {
    const float* eeg  = (const float*)d_in[0];
    const float* eye  = (const float*)d_in[1];
    const int*   mask = (const int*)d_in[2];
    const float* Weeg = (const float*)d_in[3];
    const float* Weye = (const float*)d_in[4];
    float* out = (float*)d_out;

    char* ws = (char*)d_ws;
    short* e_bf  = (short*)(ws);                       // 16 MiB
    short* v_bf  = (short*)(ws + 16777216);            // 16 MiB
    short* wbf   = (short*)(ws + 33554432);            // 256 KiB
    int*   rank  = (int*)  (ws + 33816576);            // 128 KiB
    int*   idx   = (int*)  (ws + 33947648);            // 128 KiB
    float* cb    = (float*)(ws + 34078720);            // 128 KiB
    float* psum  = (float*)(ws + 34209792);            // 512 KiB (4 j-quarters x 32 b x 1024 i)
    float* pmax  = (float*)(ws + 34734080);            // 128 KiB
    int*   Tv    = (int*)  (ws + 34865152);            // 128 B
    float* bsum  = (float*)(ws + 34865280);            // 128 B

    prep_kernel<<<544, 256, 0, stream>>>(Weeg, Weye, mask, wbf, rank, idx, Tv, cb, bsum);
    proj_kernel<<<dim3(512, 2), 256, 0, stream>>>(eeg, eye, wbf, e_bf, v_bf);
    loss_kernel<<<2048, 64, 0, stream>>>(e_bf, v_bf, cb, psum);
    pos_kernel<<<2048, 256, 0, stream>>>(e_bf, v_bf, mask, rank, idx, Tv, pmax);
    reduce_kernel<<<128, 256, 0, stream>>>(psum, pmax, mask, bsum);
    final_kernel<<<1, 64, 0, stream>>>(bsum, Tv, out);
}

// Round 4
// 159.445 us; speedup vs baseline: 1.0972x; 1.0825x over previous
//
#include <hip/hip_runtime.h>
#include <hip/hip_bf16.h>

// B=32, T=1024, D=256 fixed by the reference problem.
typedef __attribute__((ext_vector_type(8))) short bf16x8;
typedef __attribute__((ext_vector_type(4))) float f32x4;

#define INVT (1.0f/0.07f)

static __device__ __forceinline__ short f2bf(float f){
    unsigned int u = __float_as_uint(f);
    unsigned int r = (u + 0x7fffu + ((u >> 16) & 1u)) >> 16;
    return (short)r;
}
static __device__ __forceinline__ float bf2f(short s){
    return __uint_as_float(((unsigned int)(unsigned short)s) << 16);
}

// async global->LDS, 16B per lane; LDS dest = wave-uniform base + lane*16
static __device__ __forceinline__ void gld16(const void* g, void* l){
    __builtin_amdgcn_global_load_lds(
        (const __attribute__((address_space(1))) unsigned int*)g,
        (__attribute__((address_space(3))) unsigned int*)l, 16, 0, 0);
}

// ---- prep: blocks 0..511 convert W to bf16; blocks 512..543 per-batch rank scan + zero bsum
__global__ __launch_bounds__(256) void prep_kernel(const float* __restrict__ Weeg,
                                                   const float* __restrict__ Weye,
                                                   const int* __restrict__ mask,
                                                   short* __restrict__ Wout,
                                                   int* __restrict__ rank,
                                                   int* __restrict__ idx,
                                                   int* __restrict__ Tv,
                                                   float* __restrict__ cb,
                                                   float* __restrict__ bsum){
    __shared__ int ssum[256];
    int tid = threadIdx.x;
    if (blockIdx.x < 512){
        int i = blockIdx.x * 256 + tid;
        float v = (i < 65536) ? Weeg[i] : Weye[i - 65536];
        Wout[i] = f2bf(v);
        return;
    }
    int b = blockIdx.x - 512;
    if (tid == 0) bsum[b] = 0.f;
    int local[4]; int s = 0;
    #pragma unroll
    for (int q = 0; q < 4; ++q){
        int t = tid*4 + q;
        local[q] = (mask[b*1024 + t] > 0) ? 1 : 0;
        s += local[q];
    }
    ssum[tid] = s;
    __syncthreads();
    for (int off = 1; off < 256; off <<= 1){
        int add = (tid >= off) ? ssum[tid - off] : 0;
        __syncthreads();
        ssum[tid] += add;
        __syncthreads();
    }
    int run = ssum[tid] - s;
    #pragma unroll
    for (int q = 0; q < 4; ++q){
        int t = tid*4 + q;
        int g = b*1024 + t;
        run += local[q];
        rank[g] = run - 1;
        cb[g]   = local[q] ? 0.0f : -1e9f;
        if (local[q]) idx[b*1024 + run - 1] = t;
    }
    if (tid == 255) Tv[b] = ssum[255];
}

// ---- fused projection + L2 normalize, both modalities (blockIdx.y selects).
__global__ __launch_bounds__(256, 2) void proj_kernel(const float* __restrict__ Aeeg,
                                                      const float* __restrict__ Aeye,
                                                      const short* __restrict__ Wbf,
                                                      short* __restrict__ Eout,
                                                      short* __restrict__ Vout){
    __shared__ short sW[2][64 * 256];   // 2 x 32KB, XOR-swizzled in 16B blocks
    int sel = blockIdx.y;
    const float* A   = sel ? Aeye : Aeeg;
    const short* W   = Wbf + sel * 65536;
    short*       Out = sel ? Vout : Eout;

    int tid = threadIdx.x;
    int w = tid >> 6, lane = tid & 63;
    int l15 = lane & 15, lq = lane >> 4;
    int kb  = lq * 8;
    int row0 = blockIdx.x * 64;

    int ro   = lane >> 5;
    int cs   = lane & 31;
    int s7   = l15 & 7;

    #pragma unroll
    for (int p = 0; p < 8; ++p){
        int rr = (p*2 + ro) & 7;
        gld16(W + (size_t)(w*16 + p*2 + ro)*256 + (cs ^ rr)*8,
              &sW[0][(w*16 + p*2) * 256]);
    }
    #pragma unroll
    for (int p = 0; p < 8; ++p){
        int rr = (p*2 + ro) & 7;
        gld16(W + (size_t)(64 + w*16 + p*2 + ro)*256 + (cs ^ rr)*8,
              &sW[1][(w*16 + p*2) * 256]);
    }

    bf16x8 xf[8];
    {
        const float* ap = A + (size_t)(row0 + w*16 + l15) * 256 + kb;
        #pragma unroll
        for (int g = 0; g < 8; ++g){
            float4 x0 = *(const float4*)(ap + g*32);
            float4 x1 = *(const float4*)(ap + g*32 + 4);
            bf16x8 t;
            t[0]=f2bf(x0.x); t[1]=f2bf(x0.y); t[2]=f2bf(x0.z); t[3]=f2bf(x0.w);
            t[4]=f2bf(x1.x); t[5]=f2bf(x1.y); t[6]=f2bf(x1.z); t[7]=f2bf(x1.w);
            xf[g] = t;
        }
    }

    f32x4 acc[16];
    #pragma unroll
    for (int q = 0; q < 16; ++q) acc[q] = (f32x4){0.f,0.f,0.f,0.f};

    __syncthreads();

    #pragma unroll
    for (int nt = 0; nt < 4; ++nt){
        f32x4 c = acc[nt];
        int rbase = (nt*16 + l15) * 256;
        #pragma unroll
        for (int g = 0; g < 8; ++g){
            bf16x8 wf = *(const bf16x8*)&sW[0][rbase + (((g*4 + lq) ^ s7) << 3)];
            c = __builtin_amdgcn_mfma_f32_16x16x32_bf16(wf, xf[g], c, 0, 0, 0);
        }
        acc[nt] = c;
    }

    __syncthreads();

    #pragma unroll
    for (int p = 0; p < 8; ++p){
        int rr = (p*2 + ro) & 7;
        gld16(W + (size_t)(128 + w*16 + p*2 + ro)*256 + (cs ^ rr)*8,
              &sW[0][(w*16 + p*2) * 256]);
    }
    #pragma unroll
    for (int nt = 0; nt < 4; ++nt){
        f32x4 c = acc[4 + nt];
        int rbase = (nt*16 + l15) * 256;
        #pragma unroll
        for (int g = 0; g < 8; ++g){
            bf16x8 wf = *(const bf16x8*)&sW[1][rbase + (((g*4 + lq) ^ s7) << 3)];
            c = __builtin_amdgcn_mfma_f32_16x16x32_bf16(wf, xf[g], c, 0, 0, 0);
        }
        acc[4 + nt] = c;
    }

    __syncthreads();

    #pragma unroll
    for (int p = 0; p < 8; ++p){
        int rr = (p*2 + ro) & 7;
        gld16(W + (size_t)(192 + w*16 + p*2 + ro)*256 + (cs ^ rr)*8,
              &sW[1][(w*16 + p*2) * 256]);
    }
    #pragma unroll
    for (int nt = 0; nt < 4; ++nt){
        f32x4 c = acc[8 + nt];
        int rbase = (nt*16 + l15) * 256;
        #pragma unroll
        for (int g = 0; g < 8; ++g){
            bf16x8 wf = *(const bf16x8*)&sW[0][rbase + (((g*4 + lq) ^ s7) << 3)];
            c = __builtin_amdgcn_mfma_f32_16x16x32_bf16(wf, xf[g], c, 0, 0, 0);
        }
        acc[8 + nt] = c;
    }

    __syncthreads();

    #pragma unroll
    for (int nt = 0; nt < 4; ++nt){
        f32x4 c = acc[12 + nt];
        int rbase = (nt*16 + l15) * 256;
        #pragma unroll
        for (int g = 0; g < 8; ++g){
            bf16x8 wf = *(const bf16x8*)&sW[1][rbase + (((g*4 + lq) ^ s7) << 3)];
            c = __builtin_amdgcn_mfma_f32_16x16x32_bf16(wf, xf[g], c, 0, 0, 0);
        }
        acc[12 + nt] = c;
    }

    float ss = 0.f;
    #pragma unroll
    for (int q = 0; q < 16; ++q){
        #pragma unroll
        for (int r = 0; r < 4; ++r){ float x = acc[q][r]; ss += x*x; }
    }
    ss += __shfl_xor(ss, 16);
    ss += __shfl_xor(ss, 32);
    float scale = 1.0f / fmaxf(sqrtf(ss), 1e-12f);

    short* twrow = &sW[0][(w*16 + l15) * 256];
    #pragma unroll
    for (int q = 0; q < 16; ++q){
        short4 pk;
        pk.x = f2bf(acc[q][0] * scale);
        pk.y = f2bf(acc[q][1] * scale);
        pk.z = f2bf(acc[q][2] * scale);
        pk.w = f2bf(acc[q][3] * scale);
        int c    = (q >> 2) * 64 + (q & 3) * 16 + lq*4;
        int blk  = (c >> 3) ^ s7;
        *(short4*)(twrow + blk*8 + (c & 7)) = pk;
    }
    short* op = Out + (size_t)(row0 + w*16) * 256;
    #pragma unroll
    for (int p = 0; p < 8; ++p){
        int rloc = p*2 + (lane >> 5);
        int gblk = lane & 31;
        const short* tr = &sW[0][(w*16 + rloc) * 256 + ((gblk ^ (rloc & 7)) * 8)];
        *(int4*)(op + rloc*256 + gblk*8) = *(const int4*)tr;
    }
}

// ---- loss: 4-wave blocks, LDS-shared V stream. Block = 256 i-rows (64/wave,
// A-frags register-resident) x one 256-col j-quarter. V streamed in 16-row
// (8KB) tiles through a 2x8KB LDS double buffer staged with global_load_lds
// (XOR-swizzled, round-0-verified pattern); all 4 waves consume each staged
// tile -> per-CU L1 line traffic drops ~2.5x vs per-wave streaming. One
// barrier per tile; per-tile MFMA (~1200 cyc/SIMD) hides the staged-load
// latency. 512 blocks = 2/CU = 8 waves/CU. XCD-pinned: b&7 == n&7.
// psum has 4 j-quarter slices.
__global__ __launch_bounds__(256, 2) void loss_kernel(const short* __restrict__ E,
                                                      const short* __restrict__ V,
                                                      const float* __restrict__ cb,
                                                      float* __restrict__ psum){
    __shared__ short sV[2][16 * 256];           // 2 x 8KB, XOR-swizzled 16B blocks

    int n   = blockIdx.x;                       // 0..511
    int b   = (((n >> 3) & 3) << 3) | (n & 7);  // 0..31, XCD-pinned to n&7
    int itg = (n >> 5) & 3;                     // i-group: 256 rows
    int jq  = n >> 7;                           // j-quarter (0..3)

    int tid  = threadIdx.x;
    int w    = tid >> 6, lane = tid & 63;
    int l15  = lane & 15, lq = lane >> 4;
    int s7   = l15 & 7;
    int ro   = lane >> 5;
    int cs   = lane & 31;
    int j0   = jq * 256;
    int i0   = itg * 256 + w * 64;

    // stage rows for tile t: each wave issues 2 gld16 (rows p*2..p*2+1, p=w*2+c)
    const short* Vb = V + (size_t)b * 1024 * 256;

    // prologue: stage tile 0 -> buf0
    #pragma unroll
    for (int c0 = 0; c0 < 2; ++c0){
        int p  = w*2 + c0;
        int rr = (p*2 + ro) & 7;
        gld16(Vb + (size_t)(j0 + p*2 + ro)*256 + (cs ^ rr)*8,
              &sV[0][(p*2) * 256]);
    }

    // A-fragments: 64 i-rows per wave x K=256, register-resident, loaded once.
    bf16x8 af[4][8];
    {
        const short* ep = E + ((size_t)b*1024 + i0 + l15) * 256 + lq*8;
        #pragma unroll
        for (int s = 0; s < 4; ++s)
            #pragma unroll
            for (int g = 0; g < 8; ++g)
                af[s][g] = *(const bf16x8*)(ep + s*16*256 + g*32);
    }

    const float* cbp = cb + b*1024 + j0 + l15;

    float ls[4][4];
    #pragma unroll
    for (int s = 0; s < 4; ++s)
        #pragma unroll
        for (int r = 0; r < 4; ++r) ls[s][r] = 0.f;

    __syncthreads();    // tile 0 staged (barrier drains vmcnt)

    #pragma unroll 1
    for (int tp = 0; tp < 8; ++tp){
        // ---- phase A: stage tile 2tp+1 -> buf1, compute tile 2tp from buf0
        #pragma unroll
        for (int c0 = 0; c0 < 2; ++c0){
            int p  = w*2 + c0;
            int rr = (p*2 + ro) & 7;
            gld16(Vb + (size_t)(j0 + (2*tp+1)*16 + p*2 + ro)*256 + (cs ^ rr)*8,
                  &sV[1][(p*2) * 256]);
        }
        {
            float ca = cbp[2*tp*16];
            f32x4 a0 = (f32x4){0.f,0.f,0.f,0.f};
            f32x4 a1 = (f32x4){0.f,0.f,0.f,0.f};
            f32x4 a2 = (f32x4){0.f,0.f,0.f,0.f};
            f32x4 a3 = (f32x4){0.f,0.f,0.f,0.f};
            #pragma unroll
            for (int g = 0; g < 8; ++g){
                bf16x8 bf = *(const bf16x8*)&sV[0][l15*256 + (((g*4 + lq) ^ s7) << 3)];
                a0 = __builtin_amdgcn_mfma_f32_16x16x32_bf16(af[0][g], bf, a0, 0, 0, 0);
                a1 = __builtin_amdgcn_mfma_f32_16x16x32_bf16(af[1][g], bf, a1, 0, 0, 0);
                a2 = __builtin_amdgcn_mfma_f32_16x16x32_bf16(af[2][g], bf, a2, 0, 0, 0);
                a3 = __builtin_amdgcn_mfma_f32_16x16x32_bf16(af[3][g], bf, a3, 0, 0, 0);
            }
            #pragma unroll
            for (int r = 0; r < 4; ++r){
                ls[0][r] += __expf(fmaf(a0[r], INVT, ca));
                ls[1][r] += __expf(fmaf(a1[r], INVT, ca));
                ls[2][r] += __expf(fmaf(a2[r], INVT, ca));
                ls[3][r] += __expf(fmaf(a3[r], INVT, ca));
            }
        }
        __syncthreads();    // tile 2tp+1 staged; buf0 free

        // ---- phase B: stage tile 2tp+2 -> buf0 (if any), compute 2tp+1 from buf1
        if (tp < 7){
            #pragma unroll
            for (int c0 = 0; c0 < 2; ++c0){
                int p  = w*2 + c0;
                int rr = (p*2 + ro) & 7;
                gld16(Vb + (size_t)(j0 + (2*tp+2)*16 + p*2 + ro)*256 + (cs ^ rr)*8,
                      &sV[0][(p*2) * 256]);
            }
        }
        {
            float ca = cbp[(2*tp+1)*16];
            f32x4 a0 = (f32x4){0.f,0.f,0.f,0.f};
            f32x4 a1 = (f32x4){0.f,0.f,0.f,0.f};
            f32x4 a2 = (f32x4){0.f,0.f,0.f,0.f};
            f32x4 a3 = (f32x4){0.f,0.f,0.f,0.f};
            #pragma unroll
            for (int g = 0; g < 8; ++g){
                bf16x8 bf = *(const bf16x8*)&sV[1][l15*256 + (((g*4 + lq) ^ s7) << 3)];
                a0 = __builtin_amdgcn_mfma_f32_16x16x32_bf16(af[0][g], bf, a0, 0, 0, 0);
                a1 = __builtin_amdgcn_mfma_f32_16x16x32_bf16(af[1][g], bf, a1, 0, 0, 0);
                a2 = __builtin_amdgcn_mfma_f32_16x16x32_bf16(af[2][g], bf, a2, 0, 0, 0);
                a3 = __builtin_amdgcn_mfma_f32_16x16x32_bf16(af[3][g], bf, a3, 0, 0, 0);
            }
            #pragma unroll
            for (int r = 0; r < 4; ++r){
                ls[0][r] += __expf(fmaf(a0[r], INVT, ca));
                ls[1][r] += __expf(fmaf(a1[r], INVT, ca));
                ls[2][r] += __expf(fmaf(a2[r], INVT, ca));
                ls[3][r] += __expf(fmaf(a3[r], INVT, ca));
            }
        }
        __syncthreads();    // tile 2tp+2 staged; buf1 free
    }

    // reduce over the 16 lanes sharing each i-row (l15 = j within tile)
    #pragma unroll
    for (int s = 0; s < 4; ++s)
        #pragma unroll
        for (int r = 0; r < 4; ++r){
            float v = ls[s][r];
            #pragma unroll
            for (int mm = 1; mm < 16; mm <<= 1)
                v += __shfl_xor(v, mm);
            ls[s][r] = v;
        }

    if (l15 == 0){  // lanes 0,16,32,48; lq = lane>>4
        float* pp = psum + (size_t)jq*32768 + (size_t)b*1024 + i0;
        #pragma unroll
        for (int s = 0; s < 4; ++s)
            #pragma unroll
            for (int r = 0; r < 4; ++r)
                pp[s*16 + lq*4 + r] = ls[s][r];
    }
}

// ---- banded positive max: one 16-lane group per row, <=5 candidate cols via idx.
__global__ __launch_bounds__(256) void pos_kernel(const short* __restrict__ E,
                                                  const short* __restrict__ V,
                                                  const int* __restrict__ mask,
                                                  const int* __restrict__ rank,
                                                  const int* __restrict__ idx,
                                                  const int* __restrict__ Tv,
                                                  float* __restrict__ pmax){
    int tid = threadIdx.x;
    int gl  = tid & 15;
    int rf  = (blockIdx.x * 256 + tid) >> 4;   // 0..32767
    int b   = rf >> 10;
    if (mask[rf] <= 0) return;

    int ri = rank[rf];
    int tv = Tv[b];
    int lo = ri - 2; if (lo < 0) lo = 0;
    int hi = ri + 2; if (hi > tv - 1) hi = tv - 1;

    const short* epp = E + (size_t)rf * 256 + gl * 16;
    float ev[16];
    {
        bf16x8 e0 = *(const bf16x8*)epp;
        bf16x8 e1 = *(const bf16x8*)(epp + 8);
        #pragma unroll
        for (int k = 0; k < 8; ++k){ ev[k] = bf2f(e0[k]); ev[8+k] = bf2f(e1[k]); }
    }
    float pm = -1e30f;
    for (int r = lo; r <= hi; ++r){
        int j = idx[b*1024 + r];
        const short* vpp = V + ((size_t)(b*1024) + j) * 256 + gl * 16;
        bf16x8 v0 = *(const bf16x8*)vpp;
        bf16x8 v1 = *(const bf16x8*)(vpp + 8);
        float s = 0.f;
        #pragma unroll
        for (int k = 0; k < 8; ++k){
            s = fmaf(ev[k],   bf2f(v0[k]), s);
            s = fmaf(ev[8+k], bf2f(v1[k]), s);
        }
        s += __shfl_xor(s, 1);
        s += __shfl_xor(s, 2);
        s += __shfl_xor(s, 4);
        s += __shfl_xor(s, 8);
        pm = fmaxf(pm, s);
    }
    if (gl == 0) pmax[rf] = pm * INVT;
}

// ---- partial reduce: 4 blocks per b, each thread one i; psum has 4 j-quarter slices.
__global__ __launch_bounds__(256) void reduce_kernel(const float* __restrict__ psum,
                                                     const float* __restrict__ pmax,
                                                     const int* __restrict__ mask,
                                                     float* __restrict__ bsum){
    int b  = blockIdx.x >> 2;
    int i  = (blockIdx.x & 3) * 256 + threadIdx.x;
    int g  = b*1024 + i;
    float a = 0.f;
    if (mask[g] > 0){
        float ps = psum[g] + psum[g + 32768] + psum[g + 65536] + psum[g + 98304];
        a = logf(ps) - pmax[g];
    }
    #pragma unroll
    for (int m = 1; m < 64; m <<= 1) a += __shfl_xor(a, m);
    if ((threadIdx.x & 63) == 0 && a != 0.f) atomicAdd(&bsum[b], a);
}

// ---- final: out = sum_b (Tv>=2 ? bsum/Tv : 0) / 32
__global__ void final_kernel(const float* __restrict__ bsum,
                             const int* __restrict__ Tv,
                             float* __restrict__ out){
    int tid = threadIdx.x;
    float v = 0.f;
    if (tid < 32){
        int tv = Tv[tid];
        if (tv >= 2) v = bsum[tid] / (float)tv;
    }
    #pragma unroll
    for (int m = 1; m < 64; m <<= 1) v += __shfl_xor(v, m);
    if (tid == 0) out[0] = v / 32.0f;
}

extern "C" void kernel_launch(void* const* d_in, const int* in_sizes, int n_in,
                              void* d_out, int out_size, void* d_ws, size_t ws_size,
                              hipStream_t stream) {
    const float* eeg  = (const float*)d_in[0];
    const float* eye  = (const float*)d_in[1];
    const int*   mask = (const int*)d_in[2];
    const float* Weeg = (const float*)d_in[3];
    const float* Weye = (const float*)d_in[4];
    float* out = (float*)d_out;

    char* ws = (char*)d_ws;
    short* e_bf  = (short*)(ws);                       // 16 MiB
    short* v_bf  = (short*)(ws + 16777216);            // 16 MiB
    short* wbf   = (short*)(ws + 33554432);            // 256 KiB
    int*   rank  = (int*)  (ws + 33816576);            // 128 KiB
    int*   idx   = (int*)  (ws + 33947648);            // 128 KiB
    float* cb    = (float*)(ws + 34078720);            // 128 KiB
    float* psum  = (float*)(ws + 34209792);            // 512 KiB (4 j-quarters x 32 b x 1024 i)
    float* pmax  = (float*)(ws + 34734080);            // 128 KiB
    int*   Tv    = (int*)  (ws + 34865152);            // 128 B
    float* bsum  = (float*)(ws + 34865280);            // 128 B

    prep_kernel<<<544, 256, 0, stream>>>(Weeg, Weye, mask, wbf, rank, idx, Tv, cb, bsum);
    proj_kernel<<<dim3(512, 2), 256, 0, stream>>>(eeg, eye, wbf, e_bf, v_bf);
    loss_kernel<<<512, 256, 0, stream>>>(e_bf, v_bf, cb, psum);
    pos_kernel<<<2048, 256, 0, stream>>>(e_bf, v_bf, mask, rank, idx, Tv, pmax);
    reduce_kernel<<<128, 256, 0, stream>>>(psum, pmax, mask, bsum);
    final_kernel<<<1, 64, 0, stream>>>(bsum, Tv, out);
}